// Round 1
// baseline (2716.685 us; speedup 1.0000x reference)
//
#include <hip/hip_runtime.h>
#include <math.h>

// Problem constants (from setup_inputs): B=2, N=16384, K=24, d_points=64, d_model=128, POS_DIM=60
constexpr int BB  = 2;
constexpr int NN  = 16384;
constexpr int KK  = 24;
constexpr int DM  = 128;   // d_model
constexpr int DP  = 64;    // d_points

// ---------------------------------------------------------------------------
// Kernel 1: x = features @ fc1_w + fc1_b   (rows = B*N, K=64, cols=128)
// ---------------------------------------------------------------------------
__global__ __launch_bounds__(256) void fc1_kernel(
    const float* __restrict__ feat,
    const float* __restrict__ w,
    const float* __restrict__ bias,
    float* __restrict__ x)
{
    __shared__ float sw[DP * DM];   // 32 KB
    __shared__ float sf[32 * DP];   // 8 KB
    const int r0 = blockIdx.x * 32;
    for (int i = threadIdx.x; i < DP * DM; i += 256) sw[i] = w[i];
    for (int i = threadIdx.x; i < 32 * DP; i += 256) sf[i] = feat[(size_t)r0 * DP + i];
    __syncthreads();
    for (int e = threadIdx.x; e < 32 * DM; e += 256) {
        const int r = e >> 7, c = e & (DM - 1);
        float acc = bias[c];
        #pragma unroll 8
        for (int i = 0; i < DP; ++i)
            acc = fmaf(sf[r * DP + i], sw[i * DM + c], acc);
        x[(size_t)(r0 + r) * DM + c] = acc;
    }
}

// ---------------------------------------------------------------------------
// Register-blocked (24 x KD) @ (KD x 128) matmul.
// 256 threads: tx = tid&31 -> 4 cols (4*tx..4*tx+3); ty = tid>>5 -> rows {ty, ty+8, ty+16}.
// Weights streamed from global (L2-resident, broadcast-coalesced float4 per f).
// ---------------------------------------------------------------------------
template <int KD, int LDIN, bool RELU>
__device__ __forceinline__ void mm24x128(
    const float* s_in, const float* __restrict__ w,
    const float* __restrict__ bias, float* s_out, int tid)
{
    const int tx = tid & 31;
    const int ty = tid >> 5;
    const int c0 = tx * 4;
    const float4 bb = *(const float4*)&bias[c0];
    float a0x = bb.x, a0y = bb.y, a0z = bb.z, a0w = bb.w;
    float a1x = bb.x, a1y = bb.y, a1z = bb.z, a1w = bb.w;
    float a2x = bb.x, a2y = bb.y, a2z = bb.z, a2w = bb.w;
    const float* in0 = s_in + (ty     ) * LDIN;
    const float* in1 = s_in + (ty +  8) * LDIN;
    const float* in2 = s_in + (ty + 16) * LDIN;
    #pragma unroll 4
    for (int f = 0; f < KD; ++f) {
        const float4 wv = *(const float4*)&w[f * DM + c0];
        const float i0 = in0[f];
        const float i1 = in1[f];
        const float i2 = in2[f];
        a0x = fmaf(i0, wv.x, a0x); a0y = fmaf(i0, wv.y, a0y);
        a0z = fmaf(i0, wv.z, a0z); a0w = fmaf(i0, wv.w, a0w);
        a1x = fmaf(i1, wv.x, a1x); a1y = fmaf(i1, wv.y, a1y);
        a1z = fmaf(i1, wv.z, a1z); a1w = fmaf(i1, wv.w, a1w);
        a2x = fmaf(i2, wv.x, a2x); a2y = fmaf(i2, wv.y, a2y);
        a2z = fmaf(i2, wv.z, a2z); a2w = fmaf(i2, wv.w, a2w);
    }
    if (RELU) {
        a0x = fmaxf(a0x, 0.f); a0y = fmaxf(a0y, 0.f); a0z = fmaxf(a0z, 0.f); a0w = fmaxf(a0w, 0.f);
        a1x = fmaxf(a1x, 0.f); a1y = fmaxf(a1y, 0.f); a1z = fmaxf(a1z, 0.f); a1w = fmaxf(a1w, 0.f);
        a2x = fmaxf(a2x, 0.f); a2y = fmaxf(a2y, 0.f); a2z = fmaxf(a2z, 0.f); a2w = fmaxf(a2w, 0.f);
    }
    *(float4*)&s_out[(ty     ) * DM + c0] = make_float4(a0x, a0y, a0z, a0w);
    *(float4*)&s_out[(ty +  8) * DM + c0] = make_float4(a1x, a1y, a1z, a1w);
    *(float4*)&s_out[(ty + 16) * DM + c0] = make_float4(a2x, a2y, a2z, a2w);
}

// ---------------------------------------------------------------------------
// Kernel 2: fully fused per-point pipeline. One block per point (b*N+m).
// ---------------------------------------------------------------------------
__global__ __launch_bounds__(256) void fused_kernel(
    const float* __restrict__ x,        // (B*N, 128) from kernel 1 (ws)
    const float* __restrict__ xyz,
    const int*   __restrict__ knn_idx,
    const float* __restrict__ knn_xyz,
    const float* __restrict__ d1_w, const float* __restrict__ d1_b,
    const float* __restrict__ d2_w, const float* __restrict__ d2_b,
    const float* __restrict__ g1_w, const float* __restrict__ g1_b,
    const float* __restrict__ g2_w, const float* __restrict__ g2_b,
    const float* __restrict__ fc2_w, const float* __restrict__ fc2_b,
    float* __restrict__ out_res,
    float* __restrict__ out_attn)
{
    const int pt  = blockIdx.x;           // b*N + m
    const int tid = threadIdx.x;
    const int b   = pt >> 14;             // pt / N  (N = 16384)
    const size_t xbase = (size_t)b * NN * DM;

    __shared__ float s_xm[DM];            // x[m]
    __shared__ float s_kv[KK * DM];       // gathered kv
    __shared__ float s_pe[KK * DM];       // pos_enc
    __shared__ float s_A[KK * DM];        // t -> u
    __shared__ float s_B[KK * DM];        // h -> logits -> attn
    __shared__ float s_ge[KK * 64];       // g_emb (60 used, pad to 64)
    __shared__ float s_res[DM];
    __shared__ int   s_idx[KK];

    // ---- phase 0: idx, x_m, sincos pos embedding ----
    if (tid < KK)  s_idx[tid] = knn_idx[(size_t)pt * KK + tid];
    if (tid < DM)  s_xm[tid]  = x[(size_t)pt * DM + tid];
    for (int e = tid; e < KK * 30; e += 256) {
        const int n = e / 30;
        const int r = e - n * 30;
        const int c = r / 10;
        const int i = r - c * 10;
        const float p  = xyz[(size_t)pt * 3 + c] - knn_xyz[((size_t)pt * KK + n) * 3 + c];
        // omega_i = 10000^(-i/10) = 2^(-i * log2(10000)/10)
        const float om = exp2f(-(float)i * 1.3287712379549449f);
        float sv, cv;
        __sincosf(p * om, &sv, &cv);
        s_ge[n * 64 + c * 20 + i]      = sv;
        s_ge[n * 64 + c * 20 + 10 + i] = cv;
    }
    __syncthreads();

    // ---- phase 1: gather kv  +  t = relu(g_emb @ d1_w + d1_b) -> s_A ----
    for (int e = tid; e < KK * DM; e += 256) {
        const int n = e >> 7, f = e & (DM - 1);
        s_kv[e] = x[xbase + (size_t)s_idx[n] * DM + f];
    }
    mm24x128<60, 64, true>(s_ge, d1_w, d1_b, s_A, tid);
    __syncthreads();

    // ---- phase 2: pos_enc = t @ d2_w + d2_b -> s_pe ----
    mm24x128<128, 128, false>(s_A, d2_w, d2_b, s_pe, tid);
    __syncthreads();

    // ---- phase 3: h = x_m - kv + pos_enc -> s_B ----
    for (int e = tid; e < KK * DM; e += 256) {
        const int f = e & (DM - 1);
        s_B[e] = s_xm[f] - s_kv[e] + s_pe[e];
    }
    __syncthreads();

    // ---- phase 4: u = relu(h @ g1_w + g1_b) -> s_A ----
    mm24x128<128, 128, true>(s_B, g1_w, g1_b, s_A, tid);
    __syncthreads();

    // ---- phase 5: logits = u @ g2_w + g2_b -> s_B ----
    mm24x128<128, 128, false>(s_A, g2_w, g2_b, s_B, tid);
    __syncthreads();

    // ---- phase 6: per-channel softmax over K + weighted sum ----
    if (tid < DM) {
        const int f = tid;
        const float iscl = 0.08838834764831845f;  // 1/sqrt(128)
        float lv[KK];
        float mx = -1e30f;
        #pragma unroll
        for (int n = 0; n < KK; ++n) {
            lv[n] = s_B[n * DM + f] * iscl;
            mx = fmaxf(mx, lv[n]);
        }
        float sum = 0.f;
        #pragma unroll
        for (int n = 0; n < KK; ++n) {
            const float ev = __expf(lv[n] - mx);
            lv[n] = ev;
            sum += ev;
        }
        const float inv = 1.f / sum;
        float racc = 0.f;
        #pragma unroll
        for (int n = 0; n < KK; ++n) {
            const float a = lv[n] * inv;
            s_B[n * DM + f] = a;                       // attn
            racc = fmaf(a, s_kv[n * DM + f] + s_pe[n * DM + f], racc);
        }
        s_res[f] = racc;
    }
    __syncthreads();

    // ---- phase 7: write attn + final res = res @ fc2_w + fc2_b + x_m ----
    {
        float* dst = out_attn + (size_t)pt * KK * DM;
        for (int e = tid; e < KK * DM; e += 256) dst[e] = s_B[e];
    }
    if (tid < DM) {
        const int f = tid;
        float acc = fc2_b[f] + s_xm[f];
        #pragma unroll 4
        for (int g = 0; g < DM; ++g)
            acc = fmaf(s_res[g], fc2_w[g * DM + f], acc);
        out_res[(size_t)pt * DM + f] = acc;
    }
}

// ---------------------------------------------------------------------------
extern "C" void kernel_launch(void* const* d_in, const int* in_sizes, int n_in,
                              void* d_out, int out_size, void* d_ws, size_t ws_size,
                              hipStream_t stream)
{
    const float* features = (const float*)d_in[0];
    const float* xyz      = (const float*)d_in[1];
    const int*   knn_idx  = (const int*)  d_in[2];
    const float* knn_xyz  = (const float*)d_in[3];
    const float* fc1_w    = (const float*)d_in[4];
    const float* fc1_b    = (const float*)d_in[5];
    const float* fc2_w    = (const float*)d_in[6];
    const float* fc2_b    = (const float*)d_in[7];
    const float* d1_w     = (const float*)d_in[8];
    const float* d1_b     = (const float*)d_in[9];
    const float* d2_w     = (const float*)d_in[10];
    const float* d2_b     = (const float*)d_in[11];
    const float* g1_w     = (const float*)d_in[12];
    const float* g1_b     = (const float*)d_in[13];
    const float* g2_w     = (const float*)d_in[14];
    const float* g2_b     = (const float*)d_in[15];

    float* x        = (float*)d_ws;                    // B*N*128 floats = 16 MB
    float* out_res  = (float*)d_out;                   // (B,N,128)
    float* out_attn = out_res + (size_t)BB * NN * DM;  // (B,N,K,128)

    fc1_kernel<<<(BB * NN) / 32, 256, 0, stream>>>(features, fc1_w, fc1_b, x);
    fused_kernel<<<BB * NN, 256, 0, stream>>>(x, xyz, knn_idx, knn_xyz,
        d1_w, d1_b, d2_w, d2_b, g1_w, g1_b, g2_w, g2_b, fc2_w, fc2_b,
        out_res, out_attn);
}

// Round 2
// 1055.344 us; speedup vs baseline: 2.5742x; 2.5742x over previous
//
#include <hip/hip_runtime.h>
#include <hip/hip_bf16.h>
#include <math.h>

// Problem constants: B=2, N=16384, K=24, d_points=64, d_model=128, POS_DIM=60
constexpr int BB = 2;
constexpr int NN = 16384;
constexpr int KK = 24;
constexpr int DM = 128;
constexpr int DP = 64;

typedef __bf16 v8bf __attribute__((ext_vector_type(8)));
typedef float  v4f  __attribute__((ext_vector_type(4)));

// A-operand LDS leading dims: +8 bf16 pad keeps 16B alignment and shifts
// consecutive rows by 4 banks -> quad-lane ds_read_b128 is only 2-way (free).
constexpr int LDA128 = 136;
constexpr int LDA64  = 72;

// bf16 weight buffer layout in ws (element offsets from wbuf):
//   fc1t 128x64 @0, d1t 128x64 @8192, d2t 128x128 @16384,
//   g1t @32768, g2t @49152, fc2b(row-major) @65536; total 81920 bf16.
constexpr int OFF_FC1T = 0;
constexpr int OFF_D1T  = 8192;
constexpr int OFF_D2T  = 16384;
constexpr int OFF_G1T  = 32768;
constexpr int OFF_G2T  = 49152;
constexpr int OFF_FC2  = 65536;
constexpr int W_TOTAL  = 81920;

// ---------------------------------------------------------------------------
// Weight prep: transpose + cast to bf16. wbuf = d_ws + B*N*DM bf16 elems.
// ---------------------------------------------------------------------------
__global__ __launch_bounds__(256) void prep_kernel(
    const float* __restrict__ fc1_w, const float* __restrict__ fc2_w,
    const float* __restrict__ d1_w,  const float* __restrict__ d2_w,
    const float* __restrict__ g1_w,  const float* __restrict__ g2_w,
    __hip_bfloat16* __restrict__ wbuf)
{
    const int i = blockIdx.x * 256 + threadIdx.x;
    if (i >= W_TOTAL) return;
    float v;
    if (i < OFF_D1T) {                       // fc1t[n][k] = fc1_w[k][n], 64x128 src
        const int j = i, n = j >> 6, k = j & 63;
        v = fc1_w[k * DM + n];
    } else if (i < OFF_D2T) {                // d1t[n][k] = d1_w[k][n], 60x128 src, pad k>=60
        const int j = i - OFF_D1T, n = j >> 6, k = j & 63;
        v = (k < 60) ? d1_w[k * DM + n] : 0.f;
    } else if (i < OFF_G1T) {
        const int j = i - OFF_D2T, n = j >> 7, k = j & 127;
        v = d2_w[k * DM + n];
    } else if (i < OFF_G2T) {
        const int j = i - OFF_G1T, n = j >> 7, k = j & 127;
        v = g1_w[k * DM + n];
    } else if (i < OFF_FC2) {
        const int j = i - OFF_G2T, n = j >> 7, k = j & 127;
        v = g2_w[k * DM + n];
    } else {                                 // fc2 row-major cast only
        v = fc2_w[i - OFF_FC2];
    }
    wbuf[i] = __float2bfloat16(v);
}

// ---------------------------------------------------------------------------
// 32x(NKT*32) A (LDS, bf16, padded LDA) @ (NKT*32)x128 B (global bf16,
// col-major rows of length LDB) -> 2x2 tiles of 16x16 per wave.
// Wave w covers cols [c0, c0+32). MFMA layouts (verified m89/m120):
//   A: m=lane&15, k=quad*8+j ; B: k=quad*8+j, n=lane&15 ;
//   D: row=quad*4+r, col=lane&15.
// ---------------------------------------------------------------------------
template <int NKT, int LDA, int LDB>
__device__ __forceinline__ void mm_frags(
    const __hip_bfloat16* As, const __hip_bfloat16* __restrict__ Bt,
    int c0, int lane, v4f acc[2][2])
{
    const int ln = lane & 15, quad = lane >> 4;
    #pragma unroll
    for (int mt = 0; mt < 2; ++mt)
        #pragma unroll
        for (int nl = 0; nl < 2; ++nl)
            acc[mt][nl] = (v4f)0.f;
    #pragma unroll
    for (int kt = 0; kt < NKT; ++kt) {
        const int k0 = kt * 32 + quad * 8;
        const v8bf a0 = *(const v8bf*)(As + ln * LDA + k0);
        const v8bf a1 = *(const v8bf*)(As + (16 + ln) * LDA + k0);
        const v8bf b0 = *(const v8bf*)(Bt + (c0 + ln) * LDB + k0);
        const v8bf b1 = *(const v8bf*)(Bt + (c0 + 16 + ln) * LDB + k0);
        acc[0][0] = __builtin_amdgcn_mfma_f32_16x16x32_bf16(a0, b0, acc[0][0], 0, 0, 0);
        acc[0][1] = __builtin_amdgcn_mfma_f32_16x16x32_bf16(a0, b1, acc[0][1], 0, 0, 0);
        acc[1][0] = __builtin_amdgcn_mfma_f32_16x16x32_bf16(a1, b0, acc[1][0], 0, 0, 0);
        acc[1][1] = __builtin_amdgcn_mfma_f32_16x16x32_bf16(a1, b1, acc[1][1], 0, 0, 0);
    }
}

// ---------------------------------------------------------------------------
// Kernel 1: x_bf = bf16(features @ fc1_w + fc1_b), 32 rows per block, MFMA.
// ---------------------------------------------------------------------------
__global__ __launch_bounds__(256) void fc1_kernel(
    const float* __restrict__ feat,
    const __hip_bfloat16* __restrict__ fc1t,
    const float* __restrict__ fc1_b,
    __hip_bfloat16* __restrict__ x_bf)
{
    __shared__ alignas(16) __hip_bfloat16 s_f[32 * LDA64];
    const int tid = threadIdx.x;
    const int r0  = blockIdx.x * 32;
    for (int e = tid; e < 32 * DP; e += 256) {
        const int r = e >> 6, k = e & 63;
        s_f[r * LDA64 + k] = __float2bfloat16(feat[(size_t)(r0 + r) * DP + k]);
    }
    __syncthreads();
    const int w = tid >> 6, lane = tid & 63;
    const int ln = lane & 15, quad = lane >> 4;
    const int c0 = w * 32;
    v4f acc[2][2];
    mm_frags<2, LDA64, 64>(s_f, fc1t, c0, lane, acc);
    #pragma unroll
    for (int nl = 0; nl < 2; ++nl) {
        const int col = c0 + nl * 16 + ln;
        const float bb = fc1_b[col];
        #pragma unroll
        for (int mt = 0; mt < 2; ++mt)
            #pragma unroll
            for (int r = 0; r < 4; ++r) {
                const int row = mt * 16 + quad * 4 + r;
                x_bf[(size_t)(r0 + row) * DM + col] = __float2bfloat16(acc[mt][nl][r] + bb);
            }
    }
}

// ---------------------------------------------------------------------------
// Kernel 2: fused per-point pipeline with MFMA matmuls. One block per point.
// ---------------------------------------------------------------------------
__global__ __launch_bounds__(256) void fused_kernel(
    const __hip_bfloat16* __restrict__ x_bf,
    const float* __restrict__ xyz,
    const int*   __restrict__ knn_idx,
    const float* __restrict__ knn_xyz,
    const __hip_bfloat16* __restrict__ wbuf,
    const float* __restrict__ d1_b, const float* __restrict__ d2_b,
    const float* __restrict__ g1_b, const float* __restrict__ g2_b,
    const float* __restrict__ fc2_b,
    float* __restrict__ out_res,
    float* __restrict__ out_attn)
{
    __shared__ alignas(16) __hip_bfloat16 s_ge[32 * LDA64];   // 4608 B  g_emb
    __shared__ alignas(16) __hip_bfloat16 s_A [32 * LDA128];  // 8704 B  t, then u
    __shared__ alignas(16) __hip_bfloat16 s_H [32 * LDA128];  // 8704 B  h, then logits
    __shared__ float s_kv[KK * DM];                           // 12288 B kv -> kv+pe
    __shared__ float s_xm[DM];
    __shared__ float s_res[DM];
    __shared__ float s_p2[256];
    __shared__ int   s_idx[KK];

    const int pt  = blockIdx.x;
    const int tid = threadIdx.x;
    const int b   = pt >> 14;
    const int w = tid >> 6, lane = tid & 63;
    const int ln = lane & 15, quad = lane >> 4;
    const int c0 = w * 32;

    const __hip_bfloat16* d1t  = wbuf + OFF_D1T;
    const __hip_bfloat16* d2t  = wbuf + OFF_D2T;
    const __hip_bfloat16* g1t  = wbuf + OFF_G1T;
    const __hip_bfloat16* g2t  = wbuf + OFF_G2T;
    const __hip_bfloat16* fc2w = wbuf + OFF_FC2;

    // ---- phase 0a: idx, x_m, zero g_emb buffer ----
    if (tid < KK) s_idx[tid] = knn_idx[(size_t)pt * KK + tid];
    if (tid < DM) s_xm[tid]  = __bfloat162float(x_bf[(size_t)pt * DM + tid]);
    for (int i = tid; i < 32 * LDA64; i += 256) s_ge[i] = __float2bfloat16(0.f);
    __syncthreads();

    // ---- phase 0b: sincos embedding + kv gather ----
    for (int e = tid; e < KK * 30; e += 256) {
        const int n = e / 30;
        const int r = e - n * 30;
        const int c = r / 10;
        const int i = r - c * 10;
        const float p  = xyz[(size_t)pt * 3 + c] - knn_xyz[((size_t)pt * KK + n) * 3 + c];
        const float om = exp2f(-(float)i * 1.3287712379549449f); // 10000^(-i/10)
        float sv, cv;
        __sincosf(p * om, &sv, &cv);
        s_ge[n * LDA64 + c * 20 + i]      = __float2bfloat16(sv);
        s_ge[n * LDA64 + c * 20 + 10 + i] = __float2bfloat16(cv);
    }
    {
        const size_t xbase = (size_t)b * NN * DM;
        for (int e = tid; e < KK * DM; e += 256) {
            const int n = e >> 7, f = e & 127;
            s_kv[e] = __bfloat162float(x_bf[xbase + (size_t)s_idx[n] * DM + f]);
        }
    }
    __syncthreads();

    v4f acc[2][2];

    // ---- mm1: t = relu(g_emb @ d1 + d1_b) -> s_A ----
    mm_frags<2, LDA64, 64>(s_ge, d1t, c0, lane, acc);
    #pragma unroll
    for (int nl = 0; nl < 2; ++nl) {
        const int col = c0 + nl * 16 + ln;
        const float bb = d1_b[col];
        #pragma unroll
        for (int mt = 0; mt < 2; ++mt)
            #pragma unroll
            for (int r = 0; r < 4; ++r) {
                const int row = mt * 16 + quad * 4 + r;
                s_A[row * LDA128 + col] = __float2bfloat16(fmaxf(acc[mt][nl][r] + bb, 0.f));
            }
    }
    __syncthreads();

    // ---- mm2: pe = t @ d2 + d2_b; h = xm - kv + pe -> s_H; kv += pe ----
    mm_frags<4, LDA128, 128>(s_A, d2t, c0, lane, acc);
    #pragma unroll
    for (int nl = 0; nl < 2; ++nl) {
        const int col = c0 + nl * 16 + ln;
        const float bb = d2_b[col];
        const float xm = s_xm[col];
        #pragma unroll
        for (int mt = 0; mt < 2; ++mt)
            #pragma unroll
            for (int r = 0; r < 4; ++r) {
                const int row = mt * 16 + quad * 4 + r;
                const float pe = acc[mt][nl][r] + bb;
                float kvv = 0.f;
                if (row < KK) kvv = s_kv[row * DM + col];
                s_H[row * LDA128 + col] = __float2bfloat16(xm - kvv + pe);
                if (row < KK) s_kv[row * DM + col] = kvv + pe;
            }
    }
    __syncthreads();

    // ---- mm3: u = relu(h @ g1 + g1_b) -> s_A ----
    mm_frags<4, LDA128, 128>(s_H, g1t, c0, lane, acc);
    #pragma unroll
    for (int nl = 0; nl < 2; ++nl) {
        const int col = c0 + nl * 16 + ln;
        const float bb = g1_b[col];
        #pragma unroll
        for (int mt = 0; mt < 2; ++mt)
            #pragma unroll
            for (int r = 0; r < 4; ++r) {
                const int row = mt * 16 + quad * 4 + r;
                s_A[row * LDA128 + col] = __float2bfloat16(fmaxf(acc[mt][nl][r] + bb, 0.f));
            }
    }
    __syncthreads();

    // ---- mm4: logits = (u @ g2 + g2_b)/sqrt(128) -> s_H (bf16) ----
    mm_frags<4, LDA128, 128>(s_A, g2t, c0, lane, acc);
    {
        const float iscl = 0.08838834764831845f;
        #pragma unroll
        for (int nl = 0; nl < 2; ++nl) {
            const int col = c0 + nl * 16 + ln;
            const float bb = g2_b[col];
            #pragma unroll
            for (int mt = 0; mt < 2; ++mt)
                #pragma unroll
                for (int r = 0; r < 4; ++r) {
                    const int row = mt * 16 + quad * 4 + r;
                    s_H[row * LDA128 + col] = __float2bfloat16((acc[mt][nl][r] + bb) * iscl);
                }
        }
    }
    __syncthreads();

    // ---- softmax over K per channel + attn write + weighted sum ----
    if (tid < DM) {
        const int f = tid;
        float lv[KK];
        float mx = -1e30f;
        #pragma unroll
        for (int n = 0; n < KK; ++n) {
            lv[n] = __bfloat162float(s_H[n * LDA128 + f]);
            mx = fmaxf(mx, lv[n]);
        }
        float sum = 0.f;
        #pragma unroll
        for (int n = 0; n < KK; ++n) {
            const float ev = __expf(lv[n] - mx);
            lv[n] = ev;
            sum += ev;
        }
        const float inv = 1.f / sum;
        float racc = 0.f;
        float* ab = out_attn + (size_t)pt * KK * DM + f;
        #pragma unroll
        for (int n = 0; n < KK; ++n) {
            const float a = lv[n] * inv;
            ab[n * DM] = a;
            racc = fmaf(a, s_kv[n * DM + f], racc);   // kv already holds kv+pe
        }
        s_res[f] = racc;
    }
    __syncthreads();

    // ---- fc2: res @ fc2_w (split-K over 2 half-threads) + bias + x ----
    {
        const int f = tid & 127, hh = tid >> 7;
        float a2 = 0.f;
        const __hip_bfloat16* wr = fc2w + hh * 64 * DM + f;
        #pragma unroll 8
        for (int g = 0; g < 64; ++g)
            a2 = fmaf(s_res[hh * 64 + g], __bfloat162float(wr[g * DM]), a2);
        s_p2[tid] = a2;
    }
    __syncthreads();
    if (tid < DM)
        out_res[(size_t)pt * DM + tid] = s_p2[tid] + s_p2[tid + 128] + fc2_b[tid] + s_xm[tid];
}

// ---------------------------------------------------------------------------
extern "C" void kernel_launch(void* const* d_in, const int* in_sizes, int n_in,
                              void* d_out, int out_size, void* d_ws, size_t ws_size,
                              hipStream_t stream)
{
    const float* features = (const float*)d_in[0];
    const float* xyz      = (const float*)d_in[1];
    const int*   knn_idx  = (const int*)  d_in[2];
    const float* knn_xyz  = (const float*)d_in[3];
    const float* fc1_w    = (const float*)d_in[4];
    const float* fc1_b    = (const float*)d_in[5];
    const float* fc2_w    = (const float*)d_in[6];
    const float* fc2_b    = (const float*)d_in[7];
    const float* d1_w     = (const float*)d_in[8];
    const float* d1_b     = (const float*)d_in[9];
    const float* d2_w     = (const float*)d_in[10];
    const float* d2_b     = (const float*)d_in[11];
    const float* g1_w     = (const float*)d_in[12];
    const float* g1_b     = (const float*)d_in[13];
    const float* g2_w     = (const float*)d_in[14];
    const float* g2_b     = (const float*)d_in[15];

    __hip_bfloat16* x_bf = (__hip_bfloat16*)d_ws;                  // B*N*128 bf16 = 8 MB
    __hip_bfloat16* wbuf = x_bf + (size_t)BB * NN * DM;            // 160 KB bf16 weights
    float* out_res  = (float*)d_out;
    float* out_attn = out_res + (size_t)BB * NN * DM;

    prep_kernel<<<(W_TOTAL + 255) / 256, 256, 0, stream>>>(
        fc1_w, fc2_w, d1_w, d2_w, g1_w, g2_w, wbuf);
    fc1_kernel<<<(BB * NN) / 32, 256, 0, stream>>>(
        features, wbuf + OFF_FC1T, fc1_b, x_bf);
    fused_kernel<<<BB * NN, 256, 0, stream>>>(
        x_bf, xyz, knn_idx, knn_xyz, wbuf,
        d1_b, d2_b, g1_b, g2_b, fc2_b, out_res, out_attn);
}